// Round 39
// baseline (513.757 us; speedup 1.0000x reference)
//
#include <hip/hip_runtime.h>
#include <cmath>

#define B_    4
#define S_    512
#define CIN_  512
#define H_    768
#define I_    1536
#define N_    16
#define R_    48
#define K_    4
#define L_    4
#define EPS_  1e-5f
#define MROWS (B_ * S_)   // 2048
#define C_    16          // scan chunks
#define T_    (S_ / C_)   // 32 steps per chunk

typedef __attribute__((ext_vector_type(8))) short bf16x8;
typedef __attribute__((ext_vector_type(4))) float f32x4;
typedef __attribute__((ext_vector_type(4))) short s16x4;

__device__ __forceinline__ float fexpf(float x) { return __expf(x); }
__device__ __forceinline__ float siluf(float x) { return x / (1.f + __expf(-x)); }
__device__ __forceinline__ float softplusf(float x) { return x > 20.f ? x : __logf(1.f + __expf(x)); }
__device__ __forceinline__ short f2bf(float f) {
    union { float f; unsigned u; } v; v.f = f;
    unsigned r = v.u + 0x7fff + ((v.u >> 16) & 1);
    return (short)(r >> 16);
}
__device__ __forceinline__ float bf2f(short s) {
    union { float f; unsigned u; } v;
    v.u = ((unsigned)(unsigned short)s) << 16;
    return v.f;
}

#define GLOAD16(g, l) __builtin_amdgcn_global_load_lds( \
    (const __attribute__((address_space(1))) void*)(g), \
    (__attribute__((address_space(3))) void*)(l), 16, 0, 0)

// ---------------------------------------------------------------------------
// bf16 MFMA GEMM: C[M,N] = A[M,K] @ Bt[N,K]^T
// Round-39: BK=32 (was 64) -> LDS 24 KB -> 6 blocks/CU (occupancy ~50% vs
// 28%). Counters showed latency-bound (MfmaUtil 7.5%, all pipes idle); R34
// (deeper pipeline, less occupancy) and R36 (fatter tile, fewer blocks) both
// regressed -- this raises TLP instead. 64x128 tile, 4 waves, 2-buffer LDS,
// XCD-aware bijective swizzle. LDS swizzle for 4-chunk rows:
// slot = r*4 + (kq ^ ((r>>1)&3)) -> 2-way bank aliasing (free, m136);
// same involution pre-applied to global source (both-sides rule).
// gridDim.z > 1: split-K partials.  z==1 epilogues: 0 none; 1 +bias;
// 2 softplus(v+bias); 3 C += v; 4 bf16-only store; 5 softplus(v+bias)->bf16.
// ---------------------------------------------------------------------------
#define ASTRIDE (64 * 32)
#define BSTRIDE (128 * 32)

__global__ __launch_bounds__(256) void gemm_mfma(
    const short* __restrict__ A, const short* __restrict__ Bt,
    const float* __restrict__ bias, void* __restrict__ Cv_,
    int M, int N, int Kd, int lda, int ldb, int ldc, int ep)
{
    __shared__ __align__(16) short Asl[2 * ASTRIDE];
    __shared__ __align__(16) short Bsl[2 * BSTRIDE];
    const int tid = threadIdx.x;
    const int ln  = tid & 63;
    const int wv  = tid >> 6;
    const int wm  = wv >> 1, wn = wv & 1;
    const int nwg  = gridDim.x * gridDim.y;
    const int orig = blockIdx.y * gridDim.x + blockIdx.x;
    const int qq   = nwg >> 3;                 // nwg % 8 == 0 at all call sites
    const int swz  = (orig & 7) * qq + (orig >> 3);
    const int bx   = swz % gridDim.x;
    const int by   = swz / gridDim.x;
    const int row0 = by * 64;
    const int col0 = bx * 128;
    const int nz   = gridDim.z;
    const int kchunk = Kd / nz;
    const int kbeg   = blockIdx.z * kchunk;
    float* C = (float*)Cv_;
    short* Cb = (short*)Cv_;

    f32x4 acc[2][4];
    #pragma unroll
    for (int i = 0; i < 2; ++i)
        #pragma unroll
        for (int j = 0; j < 4; ++j) acc[i][j] = (f32x4){0.f, 0.f, 0.f, 0.f};

    // A tile: 64 rows x 4 chunks (8 bf16 each) = 256 slots = 1 pass of 256 thr
    const int rowa0 = tid >> 2;
    const int kpa0  = (tid & 3) ^ ((rowa0 >> 1) & 3);
    const short* ga0 = A + (size_t)(row0 + rowa0) * lda + kpa0 * 8;
    // B tile: 128 rows x 4 chunks = 512 slots = 2 passes
    const int rowb0 = tid >> 2;
    const int kpb0  = (tid & 3) ^ ((rowb0 >> 1) & 3);
    const int rowb1 = 64 + (tid >> 2);
    const int kpb1  = (tid & 3) ^ ((rowb1 >> 1) & 3);
    const short* gb0 = Bt + (size_t)(col0 + rowb0) * ldb + kpb0 * 8;
    const short* gb1 = Bt + (size_t)(col0 + rowb1) * ldb + kpb1 * 8;
    short* la0 = &Asl[(wv * 64) * 8];
    short* lb0 = &Bsl[(wv * 64) * 8];
    short* lb1 = &Bsl[(256 + wv * 64) * 8];

    const int lrow = ln & 15;
    const int kq0  = ln >> 4;
    const int nt   = kchunk / 32;

#define ISSUE_TILE(T, BI) do {                      \
    const int kI_ = kbeg + (T) * 32;                \
    GLOAD16(ga0 + kI_, la0 + (BI) * ASTRIDE);       \
    GLOAD16(gb0 + kI_, lb0 + (BI) * BSTRIDE);       \
    GLOAD16(gb1 + kI_, lb1 + (BI) * BSTRIDE);       \
} while (0)

    ISSUE_TILE(0, 0);
    __syncthreads();

    for (int t = 0; t < nt; ++t) {
        const int cur = t & 1;
        const int nxt = cur ^ 1;
        if (t + 1 < nt) ISSUE_TILE(t + 1, nxt);
        const short* Ac = &Asl[cur * ASTRIDE];
        const short* Bc = &Bsl[cur * BSTRIDE];
        bf16x8 af[2], bfr[4];
        #pragma unroll
        for (int fm = 0; fm < 2; ++fm) {
            int r = wm * 32 + fm * 16 + lrow;
            int slot = r * 4 + (kq0 ^ ((r >> 1) & 3));
            af[fm] = *(const bf16x8*)&Ac[slot * 8];
        }
        #pragma unroll
        for (int fn = 0; fn < 4; ++fn) {
            int r = wn * 64 + fn * 16 + lrow;
            int slot = r * 4 + (kq0 ^ ((r >> 1) & 3));
            bfr[fn] = *(const bf16x8*)&Bc[slot * 8];
        }
        #pragma unroll
        for (int fm = 0; fm < 2; ++fm)
            #pragma unroll
            for (int fn = 0; fn < 4; ++fn)
                acc[fm][fn] = __builtin_amdgcn_mfma_f32_16x16x32_bf16(
                    af[fm], bfr[fn], acc[fm][fn], 0, 0, 0);
        __syncthreads();
    }
#undef ISSUE_TILE

    const int erow = (ln >> 4) * 4;
    const int ecol = ln & 15;
    const size_t zoff = (size_t)blockIdx.z * M * ldc;
    #pragma unroll
    for (int fm = 0; fm < 2; ++fm) {
        #pragma unroll
        for (int fn = 0; fn < 4; ++fn) {
            int gn = col0 + wn * 64 + fn * 16 + ecol;
            if (gn >= N) continue;
            #pragma unroll
            for (int r = 0; r < 4; ++r) {
                int gm = row0 + wm * 32 + fm * 16 + erow + r;
                float v = acc[fm][fn][r];
                size_t o = (size_t)gm * ldc + gn;
                if (nz > 1) { C[zoff + o] = v; continue; }
                if (ep == 4)      { Cb[o] = f2bf(v); continue; }
                if (ep == 5)      { Cb[o] = f2bf(softplusf(v + bias[gn])); continue; }
                if (ep == 1)      v += bias[gn];
                else if (ep == 2) v  = softplusf(v + bias[gn]);
                else if (ep == 3) v += C[o];
                C[o] = v;
            }
        }
    }
}

// ---------------------------------------------------------------------------
// Split-K reduce for x_proj. mode 0 + d48 non-null: also emit bf16 copy of
// cols 0..47 into d48 [row][64] (K-padded for the dt MFMA GEMM); cols 64..79
// of the index space write the zero pad (d48 cols 48..63).
// ---------------------------------------------------------------------------
__global__ __launch_bounds__(256) void reduce_parts(
    const float* __restrict__ part, float* __restrict__ C,
    const float* __restrict__ bias, short* __restrict__ d48,
    int total, int ldc, int nz, int mode)
{
    int idx = blockIdx.x * 256 + threadIdx.x;
    if (idx >= total) return;
    size_t strideZ = (size_t)total;
    float s = 0.f;
    for (int z = 0; z < nz; ++z) s += part[idx + z * strideZ];
    if (mode == 1)      s += bias[idx % ldc];
    else if (mode == 2) s += C[idx];
    C[idx] = s;
    if (d48) {
        int row = idx / ldc, col = idx - row * ldc;
        if (col < 48)       d48[(size_t)row * 64 + col] = f2bf(s);
        else if (col >= 64) d48[(size_t)row * 64 + (col - 16)] = 0;
    }
}

// ---------------------------------------------------------------------------
// Fused split-K reduce + h update + RMSNorm (one block/row, 3 cols/thread).
// ---------------------------------------------------------------------------
__global__ __launch_bounds__(256) void reduce_h_rms(
    const float* __restrict__ part, float* __restrict__ h,
    const float* __restrict__ bias, const float* __restrict__ w,
    short* __restrict__ ubf, float* __restrict__ outf, int nz, int mode)
{
    const int row = blockIdx.x;
    const int t   = threadIdx.x;
    const size_t base = (size_t)row * H_;
    const size_t strideZ = (size_t)MROWS * H_;
    float v0, v1, v2;
    {
        size_t i0 = base + t, i1 = i0 + 256, i2 = i0 + 512;
        float s0 = 0.f, s1 = 0.f, s2 = 0.f;
        for (int z = 0; z < nz; ++z) {
            size_t zo = (size_t)z * strideZ;
            s0 += part[i0 + zo]; s1 += part[i1 + zo]; s2 += part[i2 + zo];
        }
        if (mode == 0) {
            s0 += bias[t]; s1 += bias[t + 256]; s2 += bias[t + 512];
        } else {
            s0 += h[i0]; s1 += h[i1]; s2 += h[i2];
        }
        h[i0] = s0; h[i1] = s1; h[i2] = s2;
        v0 = s0; v1 = s1; v2 = s2;
    }
    float ss = v0 * v0 + v1 * v1 + v2 * v2;
    #pragma unroll
    for (int off = 32; off > 0; off >>= 1) ss += __shfl_down(ss, off, 64);
    __shared__ float red[4];
    __shared__ float stot;
    if ((t & 63) == 0) red[t >> 6] = ss;
    __syncthreads();
    if (t == 0) stot = red[0] + red[1] + red[2] + red[3];
    __syncthreads();
    const float scale = rsqrtf(stot / (float)H_ + EPS_);
    if (mode == 2) {
        outf[base + t]       = v0 * scale * w[t];
        outf[base + t + 256] = v1 * scale * w[t + 256];
        outf[base + t + 512] = v2 * scale * w[t + 512];
    } else {
        ubf[base + t]       = f2bf(v0 * scale * w[t]);
        ubf[base + t + 256] = f2bf(v1 * scale * w[t + 256]);
        ubf[base + t + 512] = f2bf(v2 * scale * w[t + 512]);
    }
}

// ---------------------------------------------------------------------------
__global__ __launch_bounds__(256) void wtrans(
    const float* __restrict__ in0, short* __restrict__ out0,
    int Kd, int Nn, int Kpad, int Npad, size_t inStride, size_t outStride)
{
    const float* in  = in0  + blockIdx.z * inStride;
    short*       out = out0 + blockIdx.z * outStride;
    __shared__ float t[32][33];
    const int n0 = blockIdx.x * 32, k0 = blockIdx.y * 32;
    const int tx = threadIdx.x, ty = threadIdx.y;
    #pragma unroll
    for (int j = 0; j < 32; j += 8) {
        int k = k0 + ty + j, n = n0 + tx;
        t[ty + j][tx] = (k < Kd && n < Nn) ? in[(size_t)k * Nn + n] : 0.f;
    }
    __syncthreads();
    #pragma unroll
    for (int j = 0; j < 32; j += 8) {
        int np = n0 + ty + j, kp = k0 + tx;
        if (np < Npad && kp < Kpad) out[(size_t)np * Kpad + kp] = f2bf(t[tx][ty + j]);
    }
}

__global__ __launch_bounds__(256) void cast_bf16(
    const float* __restrict__ in, short* __restrict__ out, int n4)
{
    int i = blockIdx.x * 256 + threadIdx.x;
    if (i >= n4) return;
    float4 v = ((const float4*)in)[i];
    out[i * 4 + 0] = f2bf(v.x); out[i * 4 + 1] = f2bf(v.y);
    out[i * 4 + 2] = f2bf(v.z); out[i * 4 + 3] = f2bf(v.w);
}

// ---------------------------------------------------------------------------
// Causal depthwise conv1d + SiLU; bf16 in (xz), bf16 out.
// 4 sequence positions x 4 channels per thread (Round-32 win).
// ---------------------------------------------------------------------------
__global__ __launch_bounds__(256) void conv_silu_kernel(
    const short* __restrict__ xzbf, const float* __restrict__ cw,
    const float* __restrict__ cb, short* __restrict__ xcb16)
{
    int idx = blockIdx.x * 256 + threadIdx.x;        // over (MROWS/4) * (I_/4)
    if (idx >= (MROWS / 4) * (I_ / 4)) return;
    const int i4 = (idx % (I_ / 4)) * 4;
    const int g4 = idx / (I_ / 4);
    const int s0 = (g4 % (S_ / 4)) * 4;
    const int b  = g4 / (S_ / 4);
    const short* base = xzbf + (size_t)b * S_ * (2 * I_) + i4;

    float4 wch[4];
    #pragma unroll
    for (int c = 0; c < 4; ++c) wch[c] = *(const float4*)&cw[(i4 + c) * K_];
    const float4 bv = *(const float4*)&cb[i4];

    float xv[7][4];
    #pragma unroll
    for (int r = 0; r < 7; ++r) {
        int row = s0 - 3 + r;
        if (row >= 0) {
            s16x4 t = *(const s16x4*)&base[(size_t)row * (2 * I_)];
            xv[r][0] = bf2f(t[0]); xv[r][1] = bf2f(t[1]);
            xv[r][2] = bf2f(t[2]); xv[r][3] = bf2f(t[3]);
        } else {
            xv[r][0] = 0.f; xv[r][1] = 0.f; xv[r][2] = 0.f; xv[r][3] = 0.f;
        }
    }

    #pragma unroll
    for (int j = 0; j < 4; ++j) {
        float a0 = bv.x, a1 = bv.y, a2 = bv.z, a3 = bv.w;
        #pragma unroll
        for (int k = 0; k < K_; ++k) {
            const float w0 = ((const float*)&wch[0])[k];
            const float w1 = ((const float*)&wch[1])[k];
            const float w2 = ((const float*)&wch[2])[k];
            const float w3 = ((const float*)&wch[3])[k];
            a0 = fmaf(w0, xv[j + k][0], a0);
            a1 = fmaf(w1, xv[j + k][1], a1);
            a2 = fmaf(w2, xv[j + k][2], a2);
            a3 = fmaf(w3, xv[j + k][3], a3);
        }
        s16x4 r;
        r[0] = f2bf(siluf(a0)); r[1] = f2bf(siluf(a1));
        r[2] = f2bf(siluf(a2)); r[3] = f2bf(siluf(a3));
        *(s16x4*)&xcb16[((size_t)b * S_ + s0 + j) * I_ + i4] = r;
    }
}

// ---------------------------------------------------------------------------
// Chunk-parallel selective scan, 4 lanes/channel, 4 states/lane in registers.
// dt and xc staged from bf16. Step loops unrolled x4 (Round-30 win).
// Inter-chunk state (P, hend, Hstart) stored bf16 (Round-35 win).
// pass1 skips chunk 15; pass2 final iteration store-only (Round-38).
// ---------------------------------------------------------------------------
__global__ __launch_bounds__(256) void scan_pass1(
    const short* __restrict__ xcbf, const short* __restrict__ dtbf,
    const float* __restrict__ dbc, const float* __restrict__ A_log,
    short* __restrict__ P, short* __restrict__ hend)
{
    __shared__ float Bsh[T_][16];
    __shared__ float dtsh[T_][64];
    __shared__ float xcsh[T_][64];
    const int tid = threadIdx.x;
    const int lc  = tid >> 2;
    const int sub = tid & 3;
    const int ib  = blockIdx.x % (I_ / 64);
    const int rest= blockIdx.x / (I_ / 64);
    const int c   = rest % (C_ - 1);          // chunks 0..14 only
    const int b   = rest / (C_ - 1);
    const int i   = ib * 64 + lc;
    const int s0  = c * T_;

    for (int idx = tid; idx < T_ * 4; idx += 256) {
        int row = idx >> 2, q = idx & 3;
        *(float4*)&Bsh[row][q * 4] =
            *(const float4*)&dbc[((size_t)b * S_ + s0 + row) * 80 + R_ + q * 4];
    }
    for (int idx = tid; idx < T_ * 16; idx += 256) {
        int row = idx >> 4, q = idx & 15;
        size_t g = ((size_t)b * S_ + s0 + row) * I_ + ib * 64 + q * 4;
        s16x4 dv = *(const s16x4*)&dtbf[g];
        dtsh[row][q * 4 + 0] = bf2f(dv[0]);
        dtsh[row][q * 4 + 1] = bf2f(dv[1]);
        dtsh[row][q * 4 + 2] = bf2f(dv[2]);
        dtsh[row][q * 4 + 3] = bf2f(dv[3]);
        s16x4 xv = *(const s16x4*)&xcbf[g];
        xcsh[row][q * 4 + 0] = bf2f(xv[0]);
        xcsh[row][q * 4 + 1] = bf2f(xv[1]);
        xcsh[row][q * 4 + 2] = bf2f(xv[2]);
        xcsh[row][q * 4 + 3] = bf2f(xv[3]);
    }

    float4 al = *(const float4*)&A_log[i * N_ + sub * 4];
    float a[4] = {-fexpf(al.x), -fexpf(al.y), -fexpf(al.z), -fexpf(al.w)};
    float h[4] = {0.f, 0.f, 0.f, 0.f}, p[4] = {1.f, 1.f, 1.f, 1.f};
    __syncthreads();

    #pragma unroll 4
    for (int s = 0; s < T_; ++s) {
        float dtv = dtsh[s][lc];
        float xcv = xcsh[s][lc];
        float4 Bv = *(const float4*)&Bsh[s][sub * 4];
        float dx = dtv * xcv;
        #pragma unroll
        for (int j = 0; j < 4; ++j) {
            float dA = fexpf(dtv * a[j]);
            float Bj = (j == 0) ? Bv.x : (j == 1) ? Bv.y : (j == 2) ? Bv.z : Bv.w;
            h[j] = fmaf(dA, h[j], dx * Bj);
            p[j] *= dA;
        }
    }
    size_t o = (((size_t)b * C_ + c) * I_ + i) * N_ + sub * 4;
    s16x4 pv, hv;
    pv[0] = f2bf(p[0]); pv[1] = f2bf(p[1]); pv[2] = f2bf(p[2]); pv[3] = f2bf(p[3]);
    hv[0] = f2bf(h[0]); hv[1] = f2bf(h[1]); hv[2] = f2bf(h[2]); hv[3] = f2bf(h[3]);
    *(s16x4*)&P[o]    = pv;
    *(s16x4*)&hend[o] = hv;
}

__global__ __launch_bounds__(256) void scan_pass2(
    const short* __restrict__ P, const short* __restrict__ hend,
    short* __restrict__ Hstart)
{
    int idx = blockIdx.x * 256 + threadIdx.x;
    if (idx >= B_ * I_ * N_) return;
    int n = idx & 15;
    int i = (idx >> 4) % I_;
    int b = idx / (I_ * N_);
    float H = 0.f;
    #pragma unroll
    for (int c = 0; c < C_ - 1; ++c) {
        size_t o = (((size_t)b * C_ + c) * I_ + i) * (size_t)N_ + n;
        Hstart[o] = f2bf(H);
        H = fmaf(bf2f(P[o]), H, bf2f(hend[o]));
    }
    size_t o15 = (((size_t)b * C_ + (C_ - 1)) * I_ + i) * (size_t)N_ + n;
    Hstart[o15] = f2bf(H);
}

__global__ __launch_bounds__(256) void scan_pass3(
    const short* __restrict__ xcbf, const short* __restrict__ dtbf,
    const float* __restrict__ dbc, const short* __restrict__ xzbf,
    const float* __restrict__ A_log, const float* __restrict__ D,
    const short* __restrict__ Hstart, short* __restrict__ y16)
{
    __shared__ float Bsh[T_][16];
    __shared__ float Csh[T_][16];
    __shared__ float dtsh[T_][64];
    __shared__ float xcsh[T_][64];
    __shared__ float zsh[T_][64];
    __shared__ short ysh[T_][64];
    const int tid = threadIdx.x;
    const int lc  = tid >> 2;
    const int sub = tid & 3;
    const int ib  = blockIdx.x % (I_ / 64);
    const int c   = (blockIdx.x / (I_ / 64)) % C_;
    const int b   = blockIdx.x / ((I_ / 64) * C_);
    const int i   = ib * 64 + lc;
    const int s0  = c * T_;

    for (int idx = tid; idx < T_ * 4; idx += 256) {
        int row = idx >> 2, q = idx & 3;
        const float* src = &dbc[((size_t)b * S_ + s0 + row) * 80 + R_];
        *(float4*)&Bsh[row][q * 4] = *(const float4*)&src[q * 4];
        *(float4*)&Csh[row][q * 4] = *(const float4*)&src[16 + q * 4];
    }
    for (int idx = tid; idx < T_ * 16; idx += 256) {
        int row = idx >> 4, q = idx & 15;
        size_t g = ((size_t)b * S_ + s0 + row) * I_ + ib * 64 + q * 4;
        s16x4 dv = *(const s16x4*)&dtbf[g];
        dtsh[row][q * 4 + 0] = bf2f(dv[0]);
        dtsh[row][q * 4 + 1] = bf2f(dv[1]);
        dtsh[row][q * 4 + 2] = bf2f(dv[2]);
        dtsh[row][q * 4 + 3] = bf2f(dv[3]);
        s16x4 xv = *(const s16x4*)&xcbf[g];
        xcsh[row][q * 4 + 0] = bf2f(xv[0]);
        xcsh[row][q * 4 + 1] = bf2f(xv[1]);
        xcsh[row][q * 4 + 2] = bf2f(xv[2]);
        xcsh[row][q * 4 + 3] = bf2f(xv[3]);
        size_t gz = ((size_t)b * S_ + s0 + row) * (2 * I_) + I_ + ib * 64 + q * 4;
        s16x4 zv = *(const s16x4*)&xzbf[gz];
        zsh[row][q * 4 + 0] = bf2f(zv[0]);
        zsh[row][q * 4 + 1] = bf2f(zv[1]);
        zsh[row][q * 4 + 2] = bf2f(zv[2]);
        zsh[row][q * 4 + 3] = bf2f(zv[3]);
    }

    float4 al = *(const float4*)&A_log[i * N_ + sub * 4];
    float a[4] = {-fexpf(al.x), -fexpf(al.y), -fexpf(al.z), -fexpf(al.w)};
    const float Dv = D[i];

    size_t ho = (((size_t)b * C_ + c) * I_ + i) * N_ + sub * 4;
    s16x4 h0 = *(const s16x4*)&Hstart[ho];
    float h[4] = {bf2f(h0[0]), bf2f(h0[1]), bf2f(h0[2]), bf2f(h0[3])};
    __syncthreads();

    #pragma unroll 4
    for (int s = 0; s < T_; ++s) {
        float dtv = dtsh[s][lc];
        float xcv = xcsh[s][lc];
        float4 Bv = *(const float4*)&Bsh[s][sub * 4];
        float4 Cv = *(const float4*)&Csh[s][sub * 4];
        float dx = dtv * xcv;
        float yv;
        {
            float dA0 = fexpf(dtv * a[0]);
            float dA1 = fexpf(dtv * a[1]);
            float dA2 = fexpf(dtv * a[2]);
            float dA3 = fexpf(dtv * a[3]);
            h[0] = fmaf(dA0, h[0], dx * Bv.x);
            h[1] = fmaf(dA1, h[1], dx * Bv.y);
            h[2] = fmaf(dA2, h[2], dx * Bv.z);
            h[3] = fmaf(dA3, h[3], dx * Bv.w);
            yv = h[0] * Cv.x;
            yv = fmaf(h[1], Cv.y, yv);
            yv = fmaf(h[2], Cv.z, yv);
            yv = fmaf(h[3], Cv.w, yv);
        }
        yv += __shfl_xor(yv, 1, 4);
        yv += __shfl_xor(yv, 2, 4);
        if (sub == 0) {
            float zv = zsh[s][lc];
            ysh[s][lc] = f2bf((yv + xcv * Dv) * siluf(zv));
        }
    }
    __syncthreads();
    for (int idx = tid; idx < T_ * 16; idx += 256) {
        int row = idx >> 4, q = idx & 15;
        size_t g = ((size_t)b * S_ + s0 + row) * I_ + ib * 64 + q * 4;
        *(s16x4*)&y16[g] = *(const s16x4*)&ysh[row][q * 4];
    }
}

// ---------------------------------------------------------------------------
extern "C" void kernel_launch(void* const* d_in, const int* in_sizes, int n_in,
                              void* d_out, int out_size, void* d_ws, size_t ws_size,
                              hipStream_t stream)
{
    const float* x     = (const float*)d_in[0];
    const float* W_in  = (const float*)d_in[1];
    const float* b_in  = (const float*)d_in[2];
    const float* norm_w= (const float*)d_in[3];
    const float* ipw   = (const float*)d_in[4];
    const float* cw    = (const float*)d_in[5];
    const float* cb    = (const float*)d_in[6];
    const float* xpw   = (const float*)d_in[7];
    const float* dpw   = (const float*)d_in[8];
    const float* dpb   = (const float*)d_in[9];
    const float* A_log = (const float*)d_in[10];
    const float* Dp    = (const float*)d_in[11];
    const float* opw   = (const float*)d_in[12];
    const float* nfw   = (const float*)d_in[13];
    float* out = (float*)d_out;

    // fp32 scratch
    float* wsf  = (float*)d_ws;
    float* h    = wsf;  wsf += (size_t)MROWS * H_;
    float* parts= wsf;  wsf += (size_t)3 * MROWS * H_;
    float* dbcb = wsf;  wsf += (size_t)MROWS * 80;
    // bf16 scratch
    short* wss   = (short*)wsf;
    short* x_bf  = wss;  wss += (size_t)MROWS * CIN_;
    short* u_bf  = wss;  wss += (size_t)MROWS * H_;
    short* xz_bf = wss;  wss += (size_t)MROWS * 2 * I_;
    short* xc_bf = wss;  wss += (size_t)MROWS * I_;
    short* dt_bf = wss;  wss += (size_t)MROWS * I_;
    short* y_bf  = wss;  wss += (size_t)MROWS * I_;
    short* dbc48 = wss;  wss += (size_t)MROWS * 64;
    short* Pb    = wss;  wss += (size_t)B_ * C_ * I_ * N_;
    short* heb   = wss;  wss += (size_t)B_ * C_ * I_ * N_;
    short* Hsb   = wss;  wss += (size_t)B_ * C_ * I_ * N_;
    short* WinT  = wss;  wss += (size_t)H_ * CIN_;
    short* ipwT  = wss;  wss += (size_t)L_ * 2 * I_ * H_;
    short* xpwT  = wss;  wss += (size_t)L_ * 128 * I_;
    short* opwT  = wss;  wss += (size_t)L_ * H_ * I_;
    short* dpwT  = wss;  wss += (size_t)L_ * I_ * 64;

    // x_proj split-K partials alias `parts` (dead between out_proj uses):
    // 8*2048*80 floats (5.2MB) <= 3*2048*768 floats (18.9MB)
    float* part_x = parts;

    const dim3 blk(256);
    const dim3 tblk(32, 8);

    // one-time conversions (consolidated)
    cast_bf16<<<(MROWS * CIN_ / 4 + 255) / 256, blk, 0, stream>>>(x, x_bf, MROWS * CIN_ / 4);
    wtrans<<<dim3(H_ / 32, CIN_ / 32, 1), tblk, 0, stream>>>(
        W_in, WinT, CIN_, H_, CIN_, H_, 0, 0);
    wtrans<<<dim3(2 * I_ / 32, H_ / 32, L_), tblk, 0, stream>>>(
        ipw, ipwT, H_, 2 * I_, H_, 2 * I_, (size_t)H_ * 2 * I_, (size_t)2 * I_ * H_);
    wtrans<<<dim3(128 / 32, I_ / 32, L_), tblk, 0, stream>>>(
        xpw, xpwT, I_, 80, I_, 128, (size_t)I_ * 80, (size_t)128 * I_);
    wtrans<<<dim3(H_ / 32, I_ / 32, L_), tblk, 0, stream>>>(
        opw, opwT, I_, H_, I_, H_, (size_t)I_ * H_, (size_t)H_ * I_);
    // dpw (L,48,I) -> bf16 (I,64) K-padded transpose (zeros in cols 48..63)
    wtrans<<<dim3(I_ / 32, 64 / 32, L_), tblk, 0, stream>>>(
        dpw, dpwT, R_, I_, 64, I_, (size_t)R_ * I_, (size_t)I_ * 64);

    // h = x @ W_in + b_in (split-K=2), fused reduce+bias+rms -> u_bf (layer 0)
    gemm_mfma<<<dim3(H_ / 128, MROWS / 64, 2), blk, 0, stream>>>(
        x_bf, WinT, nullptr, parts, MROWS, H_, CIN_, CIN_, CIN_, H_, 0);
    reduce_h_rms<<<MROWS, blk, 0, stream>>>(
        parts, h, b_in, norm_w, u_bf, nullptr, 2, 0);

    const int scan1_blocks = B_ * (C_ - 1) * (I_ / 64);   // 1440
    const int scan3_blocks = B_ * C_ * (I_ / 64);         // 1536
    const int conv_blocks = ((MROWS / 4) * (I_ / 4) + 255) / 256;   // 768

    for (int l = 0; l < L_; ++l) {
        // xz = u @ in_proj_w  -> bf16 only (ep=4)
        gemm_mfma<<<dim3(2 * I_ / 128, MROWS / 64, 1), blk, 0, stream>>>(
            u_bf, ipwT + (size_t)l * 2 * I_ * H_, nullptr, xz_bf,
            MROWS, 2 * I_, H_, H_, H_, 2 * I_, 4);
        conv_silu_kernel<<<conv_blocks, blk, 0, stream>>>(
            xz_bf, cw + l * I_ * K_, cb + l * I_, xc_bf);
        gemm_mfma<<<dim3(1, MROWS / 64, 8), blk, 0, stream>>>(
            xc_bf, xpwT + (size_t)l * 128 * I_, nullptr, part_x,
            MROWS, 80, I_, I_, I_, 80, 0);
        reduce_parts<<<(MROWS * 80 + 255) / 256, blk, 0, stream>>>(
            part_x, dbcb, nullptr, dbc48, MROWS * 80, 80, 8, 0);
        // dt = softplus(dbc48 @ dpwT^T + dpb) -> bf16  (MFMA, K=64 padded)
        gemm_mfma<<<dim3(I_ / 128, MROWS / 64, 1), blk, 0, stream>>>(
            dbc48, dpwT + (size_t)l * I_ * 64, dpb + (size_t)l * I_, dt_bf,
            MROWS, I_, 64, 64, 64, I_, 5);
        // chunked selective scan (bf16 inter-chunk state)
        scan_pass1<<<scan1_blocks, blk, 0, stream>>>(
            xc_bf, dt_bf, dbcb, A_log + l * I_ * N_, Pb, heb);
        scan_pass2<<<(B_ * I_ * N_ + 255) / 256, blk, 0, stream>>>(Pb, heb, Hsb);
        scan_pass3<<<scan3_blocks, blk, 0, stream>>>(
            xc_bf, dt_bf, dbcb, xz_bf, A_log + l * I_ * N_, Dp + l * I_, Hsb, y_bf);
        // h += y @ out_proj_w (split-K=3), fused reduce + h + rms
        gemm_mfma<<<dim3(H_ / 128, MROWS / 64, 3), blk, 0, stream>>>(
            y_bf, opwT + (size_t)l * H_ * I_, nullptr, parts,
            MROWS, H_, I_, I_, I_, H_, 0);
        if (l < L_ - 1) {
            reduce_h_rms<<<MROWS, blk, 0, stream>>>(
                parts, h, nullptr, norm_w + (l + 1) * H_, u_bf, nullptr, 3, 1);
        } else {
            reduce_h_rms<<<MROWS, blk, 0, stream>>>(
                parts, h, nullptr, nfw, nullptr, out, 3, 2);
        }
    }
}

// Round 40
// 475.755 us; speedup vs baseline: 1.0799x; 1.0799x over previous
//
#include <hip/hip_runtime.h>
#include <cmath>

#define B_    4
#define S_    512
#define CIN_  512
#define H_    768
#define I_    1536
#define N_    16
#define R_    48
#define K_    4
#define L_    4
#define EPS_  1e-5f
#define MROWS (B_ * S_)   // 2048
#define C_    16          // scan chunks
#define T_    (S_ / C_)   // 32 steps per chunk

typedef __attribute__((ext_vector_type(8))) short bf16x8;
typedef __attribute__((ext_vector_type(4))) float f32x4;
typedef __attribute__((ext_vector_type(4))) short s16x4;

__device__ __forceinline__ float fexpf(float x) { return __expf(x); }
__device__ __forceinline__ float siluf(float x) { return x / (1.f + __expf(-x)); }
__device__ __forceinline__ float softplusf(float x) { return x > 20.f ? x : __logf(1.f + __expf(x)); }
__device__ __forceinline__ short f2bf(float f) {
    union { float f; unsigned u; } v; v.f = f;
    unsigned r = v.u + 0x7fff + ((v.u >> 16) & 1);
    return (short)(r >> 16);
}
__device__ __forceinline__ float bf2f(short s) {
    union { float f; unsigned u; } v;
    v.u = ((unsigned)(unsigned short)s) << 16;
    return v.f;
}

#define GLOAD16(g, l) __builtin_amdgcn_global_load_lds( \
    (const __attribute__((address_space(1))) void*)(g), \
    (__attribute__((address_space(3))) void*)(l), 16, 0, 0)

// ---------------------------------------------------------------------------
// bf16 MFMA GEMM: C[M,N] = A[M,K] @ Bt[N,K]^T   (best measured config:
// 64x128 tile, BK=64, 3 blocks/CU. Ruled out by measurement: 128x128 (R36,
// grid too small), 3-buffer vmcnt pipeline (R34, occupancy loss), BK=32
// (R39, grid-bound occupancy + 2x barriers). ~216 TF here matches the m102
// shape curve for this structure at effective K<=1536 -- structural floor.)
// BK=64, 4 waves, 2-buffer LDS, XCD-aware bijective swizzle.
// gridDim.z > 1: split-K partials.  z==1 epilogues: 0 none; 1 +bias;
// 2 softplus(v+bias); 3 C += v; 4 bf16-only store; 5 softplus(v+bias)->bf16.
// ---------------------------------------------------------------------------
#define ASTRIDE (64 * 64)
#define BSTRIDE (128 * 64)

__global__ __launch_bounds__(256) void gemm_mfma(
    const short* __restrict__ A, const short* __restrict__ Bt,
    const float* __restrict__ bias, void* __restrict__ Cv_,
    int M, int N, int Kd, int lda, int ldb, int ldc, int ep)
{
    __shared__ __align__(16) short Asl[2 * ASTRIDE];
    __shared__ __align__(16) short Bsl[2 * BSTRIDE];
    const int tid = threadIdx.x;
    const int ln  = tid & 63;
    const int wv  = tid >> 6;
    const int wm  = wv >> 1, wn = wv & 1;
    const int nwg  = gridDim.x * gridDim.y;
    const int orig = blockIdx.y * gridDim.x + blockIdx.x;
    const int qq   = nwg >> 3;                 // nwg % 8 == 0 at all call sites
    const int swz  = (orig & 7) * qq + (orig >> 3);
    const int bx   = swz % gridDim.x;
    const int by   = swz / gridDim.x;
    const int row0 = by * 64;
    const int col0 = bx * 128;
    const int nz   = gridDim.z;
    const int kchunk = Kd / nz;
    const int kbeg   = blockIdx.z * kchunk;
    float* C = (float*)Cv_;
    short* Cb = (short*)Cv_;

    f32x4 acc[2][4];
    #pragma unroll
    for (int i = 0; i < 2; ++i)
        #pragma unroll
        for (int j = 0; j < 4; ++j) acc[i][j] = (f32x4){0.f, 0.f, 0.f, 0.f};

    const int ca0 = tid, ca1 = tid + 256;
    const int rowa0 = ca0 >> 3, kpa0 = (ca0 & 7) ^ (rowa0 & 7);
    const int rowa1 = ca1 >> 3, kpa1 = (ca1 & 7) ^ (rowa1 & 7);
    const short* ga0 = A + (size_t)(row0 + rowa0) * lda + kpa0 * 8;
    const short* ga1 = A + (size_t)(row0 + rowa1) * lda + kpa1 * 8;
    const int cb0 = tid, cb1 = tid + 256, cb2 = tid + 512, cb3 = tid + 768;
    const int rowb0 = cb0 >> 3, kpb0 = (cb0 & 7) ^ (rowb0 & 7);
    const int rowb1 = cb1 >> 3, kpb1 = (cb1 & 7) ^ (rowb1 & 7);
    const int rowb2 = cb2 >> 3, kpb2 = (cb2 & 7) ^ (rowb2 & 7);
    const int rowb3 = cb3 >> 3, kpb3 = (cb3 & 7) ^ (rowb3 & 7);
    const short* gb0 = Bt + (size_t)(col0 + rowb0) * ldb + kpb0 * 8;
    const short* gb1 = Bt + (size_t)(col0 + rowb1) * ldb + kpb1 * 8;
    const short* gb2 = Bt + (size_t)(col0 + rowb2) * ldb + kpb2 * 8;
    const short* gb3 = Bt + (size_t)(col0 + rowb3) * ldb + kpb3 * 8;
    short* la0 = &Asl[(wv * 64) * 8];
    short* la1 = &Asl[(256 + wv * 64) * 8];
    short* lb0 = &Bsl[(wv * 64) * 8];
    short* lb1 = &Bsl[(256 + wv * 64) * 8];
    short* lb2 = &Bsl[(512 + wv * 64) * 8];
    short* lb3 = &Bsl[(768 + wv * 64) * 8];

    const int lrow = ln & 15;
    const int kq0  = ln >> 4;
    const int nt   = kchunk / 64;

#define ISSUE_TILE(T, BI) do {                      \
    const int kI_ = kbeg + (T) * 64;                \
    GLOAD16(ga0 + kI_, la0 + (BI) * ASTRIDE);       \
    GLOAD16(ga1 + kI_, la1 + (BI) * ASTRIDE);       \
    GLOAD16(gb0 + kI_, lb0 + (BI) * BSTRIDE);       \
    GLOAD16(gb1 + kI_, lb1 + (BI) * BSTRIDE);       \
    GLOAD16(gb2 + kI_, lb2 + (BI) * BSTRIDE);       \
    GLOAD16(gb3 + kI_, lb3 + (BI) * BSTRIDE);       \
} while (0)

    ISSUE_TILE(0, 0);
    __syncthreads();

    for (int t = 0; t < nt; ++t) {
        const int cur = t & 1;
        const int nxt = cur ^ 1;
        if (t + 1 < nt) ISSUE_TILE(t + 1, nxt);
        const short* Ac = &Asl[cur * ASTRIDE];
        const short* Bc = &Bsl[cur * BSTRIDE];
        #pragma unroll
        for (int kk = 0; kk < 2; ++kk) {
            const int kq = kk * 4 + kq0;
            bf16x8 af[2], bfr[4];
            #pragma unroll
            for (int fm = 0; fm < 2; ++fm) {
                int r = wm * 32 + fm * 16 + lrow;
                int slot = r * 8 + (kq ^ (r & 7));
                af[fm] = *(const bf16x8*)&Ac[slot * 8];
            }
            #pragma unroll
            for (int fn = 0; fn < 4; ++fn) {
                int r = wn * 64 + fn * 16 + lrow;
                int slot = r * 8 + (kq ^ (r & 7));
                bfr[fn] = *(const bf16x8*)&Bc[slot * 8];
            }
            #pragma unroll
            for (int fm = 0; fm < 2; ++fm)
                #pragma unroll
                for (int fn = 0; fn < 4; ++fn)
                    acc[fm][fn] = __builtin_amdgcn_mfma_f32_16x16x32_bf16(
                        af[fm], bfr[fn], acc[fm][fn], 0, 0, 0);
        }
        __syncthreads();
    }
#undef ISSUE_TILE

    const int erow = (ln >> 4) * 4;
    const int ecol = ln & 15;
    const size_t zoff = (size_t)blockIdx.z * M * ldc;
    #pragma unroll
    for (int fm = 0; fm < 2; ++fm) {
        #pragma unroll
        for (int fn = 0; fn < 4; ++fn) {
            int gn = col0 + wn * 64 + fn * 16 + ecol;
            if (gn >= N) continue;
            #pragma unroll
            for (int r = 0; r < 4; ++r) {
                int gm = row0 + wm * 32 + fm * 16 + erow + r;
                float v = acc[fm][fn][r];
                size_t o = (size_t)gm * ldc + gn;
                if (nz > 1) { C[zoff + o] = v; continue; }
                if (ep == 4)      { Cb[o] = f2bf(v); continue; }
                if (ep == 5)      { Cb[o] = f2bf(softplusf(v + bias[gn])); continue; }
                if (ep == 1)      v += bias[gn];
                else if (ep == 2) v  = softplusf(v + bias[gn]);
                else if (ep == 3) v += C[o];
                C[o] = v;
            }
        }
    }
}

// ---------------------------------------------------------------------------
// Split-K reduce for x_proj. mode 0 + d48 non-null: also emit bf16 copy of
// cols 0..47 into d48 [row][64] (K-padded for the dt MFMA GEMM); cols 64..79
// of the index space write the zero pad (d48 cols 48..63).
// ---------------------------------------------------------------------------
__global__ __launch_bounds__(256) void reduce_parts(
    const float* __restrict__ part, float* __restrict__ C,
    const float* __restrict__ bias, short* __restrict__ d48,
    int total, int ldc, int nz, int mode)
{
    int idx = blockIdx.x * 256 + threadIdx.x;
    if (idx >= total) return;
    size_t strideZ = (size_t)total;
    float s = 0.f;
    for (int z = 0; z < nz; ++z) s += part[idx + z * strideZ];
    if (mode == 1)      s += bias[idx % ldc];
    else if (mode == 2) s += C[idx];
    C[idx] = s;
    if (d48) {
        int row = idx / ldc, col = idx - row * ldc;
        if (col < 48)       d48[(size_t)row * 64 + col] = f2bf(s);
        else if (col >= 64) d48[(size_t)row * 64 + (col - 16)] = 0;
    }
}

// ---------------------------------------------------------------------------
// Fused split-K reduce + h update + RMSNorm (one block/row, 3 cols/thread).
// ---------------------------------------------------------------------------
__global__ __launch_bounds__(256) void reduce_h_rms(
    const float* __restrict__ part, float* __restrict__ h,
    const float* __restrict__ bias, const float* __restrict__ w,
    short* __restrict__ ubf, float* __restrict__ outf, int nz, int mode)
{
    const int row = blockIdx.x;
    const int t   = threadIdx.x;
    const size_t base = (size_t)row * H_;
    const size_t strideZ = (size_t)MROWS * H_;
    float v0, v1, v2;
    {
        size_t i0 = base + t, i1 = i0 + 256, i2 = i0 + 512;
        float s0 = 0.f, s1 = 0.f, s2 = 0.f;
        for (int z = 0; z < nz; ++z) {
            size_t zo = (size_t)z * strideZ;
            s0 += part[i0 + zo]; s1 += part[i1 + zo]; s2 += part[i2 + zo];
        }
        if (mode == 0) {
            s0 += bias[t]; s1 += bias[t + 256]; s2 += bias[t + 512];
        } else {
            s0 += h[i0]; s1 += h[i1]; s2 += h[i2];
        }
        h[i0] = s0; h[i1] = s1; h[i2] = s2;
        v0 = s0; v1 = s1; v2 = s2;
    }
    float ss = v0 * v0 + v1 * v1 + v2 * v2;
    #pragma unroll
    for (int off = 32; off > 0; off >>= 1) ss += __shfl_down(ss, off, 64);
    __shared__ float red[4];
    __shared__ float stot;
    if ((t & 63) == 0) red[t >> 6] = ss;
    __syncthreads();
    if (t == 0) stot = red[0] + red[1] + red[2] + red[3];
    __syncthreads();
    const float scale = rsqrtf(stot / (float)H_ + EPS_);
    if (mode == 2) {
        outf[base + t]       = v0 * scale * w[t];
        outf[base + t + 256] = v1 * scale * w[t + 256];
        outf[base + t + 512] = v2 * scale * w[t + 512];
    } else {
        ubf[base + t]       = f2bf(v0 * scale * w[t]);
        ubf[base + t + 256] = f2bf(v1 * scale * w[t + 256]);
        ubf[base + t + 512] = f2bf(v2 * scale * w[t + 512]);
    }
}

// ---------------------------------------------------------------------------
__global__ __launch_bounds__(256) void wtrans(
    const float* __restrict__ in0, short* __restrict__ out0,
    int Kd, int Nn, int Kpad, int Npad, size_t inStride, size_t outStride)
{
    const float* in  = in0  + blockIdx.z * inStride;
    short*       out = out0 + blockIdx.z * outStride;
    __shared__ float t[32][33];
    const int n0 = blockIdx.x * 32, k0 = blockIdx.y * 32;
    const int tx = threadIdx.x, ty = threadIdx.y;
    #pragma unroll
    for (int j = 0; j < 32; j += 8) {
        int k = k0 + ty + j, n = n0 + tx;
        t[ty + j][tx] = (k < Kd && n < Nn) ? in[(size_t)k * Nn + n] : 0.f;
    }
    __syncthreads();
    #pragma unroll
    for (int j = 0; j < 32; j += 8) {
        int np = n0 + ty + j, kp = k0 + tx;
        if (np < Npad && kp < Kpad) out[(size_t)np * Kpad + kp] = f2bf(t[tx][ty + j]);
    }
}

__global__ __launch_bounds__(256) void cast_bf16(
    const float* __restrict__ in, short* __restrict__ out, int n4)
{
    int i = blockIdx.x * 256 + threadIdx.x;
    if (i >= n4) return;
    float4 v = ((const float4*)in)[i];
    out[i * 4 + 0] = f2bf(v.x); out[i * 4 + 1] = f2bf(v.y);
    out[i * 4 + 2] = f2bf(v.z); out[i * 4 + 3] = f2bf(v.w);
}

// ---------------------------------------------------------------------------
// Causal depthwise conv1d + SiLU; bf16 in (xz), bf16 out.
// 4 sequence positions x 4 channels per thread (Round-32 win).
// ---------------------------------------------------------------------------
__global__ __launch_bounds__(256) void conv_silu_kernel(
    const short* __restrict__ xzbf, const float* __restrict__ cw,
    const float* __restrict__ cb, short* __restrict__ xcb16)
{
    int idx = blockIdx.x * 256 + threadIdx.x;        // over (MROWS/4) * (I_/4)
    if (idx >= (MROWS / 4) * (I_ / 4)) return;
    const int i4 = (idx % (I_ / 4)) * 4;
    const int g4 = idx / (I_ / 4);
    const int s0 = (g4 % (S_ / 4)) * 4;
    const int b  = g4 / (S_ / 4);
    const short* base = xzbf + (size_t)b * S_ * (2 * I_) + i4;

    float4 wch[4];
    #pragma unroll
    for (int c = 0; c < 4; ++c) wch[c] = *(const float4*)&cw[(i4 + c) * K_];
    const float4 bv = *(const float4*)&cb[i4];

    float xv[7][4];
    #pragma unroll
    for (int r = 0; r < 7; ++r) {
        int row = s0 - 3 + r;
        if (row >= 0) {
            s16x4 t = *(const s16x4*)&base[(size_t)row * (2 * I_)];
            xv[r][0] = bf2f(t[0]); xv[r][1] = bf2f(t[1]);
            xv[r][2] = bf2f(t[2]); xv[r][3] = bf2f(t[3]);
        } else {
            xv[r][0] = 0.f; xv[r][1] = 0.f; xv[r][2] = 0.f; xv[r][3] = 0.f;
        }
    }

    #pragma unroll
    for (int j = 0; j < 4; ++j) {
        float a0 = bv.x, a1 = bv.y, a2 = bv.z, a3 = bv.w;
        #pragma unroll
        for (int k = 0; k < K_; ++k) {
            const float w0 = ((const float*)&wch[0])[k];
            const float w1 = ((const float*)&wch[1])[k];
            const float w2 = ((const float*)&wch[2])[k];
            const float w3 = ((const float*)&wch[3])[k];
            a0 = fmaf(w0, xv[j + k][0], a0);
            a1 = fmaf(w1, xv[j + k][1], a1);
            a2 = fmaf(w2, xv[j + k][2], a2);
            a3 = fmaf(w3, xv[j + k][3], a3);
        }
        s16x4 r;
        r[0] = f2bf(siluf(a0)); r[1] = f2bf(siluf(a1));
        r[2] = f2bf(siluf(a2)); r[3] = f2bf(siluf(a3));
        *(s16x4*)&xcb16[((size_t)b * S_ + s0 + j) * I_ + i4] = r;
    }
}

// ---------------------------------------------------------------------------
// Chunk-parallel selective scan, 4 lanes/channel, 4 states/lane in registers.
// dt and xc staged from bf16. Step loops unrolled x4 (Round-30 win).
// Inter-chunk state (P, hend, Hstart) stored bf16 (Round-35 win).
// pass1 skips chunk 15; pass2 final iteration store-only (Round-38).
// ---------------------------------------------------------------------------
__global__ __launch_bounds__(256) void scan_pass1(
    const short* __restrict__ xcbf, const short* __restrict__ dtbf,
    const float* __restrict__ dbc, const float* __restrict__ A_log,
    short* __restrict__ P, short* __restrict__ hend)
{
    __shared__ float Bsh[T_][16];
    __shared__ float dtsh[T_][64];
    __shared__ float xcsh[T_][64];
    const int tid = threadIdx.x;
    const int lc  = tid >> 2;
    const int sub = tid & 3;
    const int ib  = blockIdx.x % (I_ / 64);
    const int rest= blockIdx.x / (I_ / 64);
    const int c   = rest % (C_ - 1);          // chunks 0..14 only
    const int b   = rest / (C_ - 1);
    const int i   = ib * 64 + lc;
    const int s0  = c * T_;

    for (int idx = tid; idx < T_ * 4; idx += 256) {
        int row = idx >> 2, q = idx & 3;
        *(float4*)&Bsh[row][q * 4] =
            *(const float4*)&dbc[((size_t)b * S_ + s0 + row) * 80 + R_ + q * 4];
    }
    for (int idx = tid; idx < T_ * 16; idx += 256) {
        int row = idx >> 4, q = idx & 15;
        size_t g = ((size_t)b * S_ + s0 + row) * I_ + ib * 64 + q * 4;
        s16x4 dv = *(const s16x4*)&dtbf[g];
        dtsh[row][q * 4 + 0] = bf2f(dv[0]);
        dtsh[row][q * 4 + 1] = bf2f(dv[1]);
        dtsh[row][q * 4 + 2] = bf2f(dv[2]);
        dtsh[row][q * 4 + 3] = bf2f(dv[3]);
        s16x4 xv = *(const s16x4*)&xcbf[g];
        xcsh[row][q * 4 + 0] = bf2f(xv[0]);
        xcsh[row][q * 4 + 1] = bf2f(xv[1]);
        xcsh[row][q * 4 + 2] = bf2f(xv[2]);
        xcsh[row][q * 4 + 3] = bf2f(xv[3]);
    }

    float4 al = *(const float4*)&A_log[i * N_ + sub * 4];
    float a[4] = {-fexpf(al.x), -fexpf(al.y), -fexpf(al.z), -fexpf(al.w)};
    float h[4] = {0.f, 0.f, 0.f, 0.f}, p[4] = {1.f, 1.f, 1.f, 1.f};
    __syncthreads();

    #pragma unroll 4
    for (int s = 0; s < T_; ++s) {
        float dtv = dtsh[s][lc];
        float xcv = xcsh[s][lc];
        float4 Bv = *(const float4*)&Bsh[s][sub * 4];
        float dx = dtv * xcv;
        #pragma unroll
        for (int j = 0; j < 4; ++j) {
            float dA = fexpf(dtv * a[j]);
            float Bj = (j == 0) ? Bv.x : (j == 1) ? Bv.y : (j == 2) ? Bv.z : Bv.w;
            h[j] = fmaf(dA, h[j], dx * Bj);
            p[j] *= dA;
        }
    }
    size_t o = (((size_t)b * C_ + c) * I_ + i) * N_ + sub * 4;
    s16x4 pv, hv;
    pv[0] = f2bf(p[0]); pv[1] = f2bf(p[1]); pv[2] = f2bf(p[2]); pv[3] = f2bf(p[3]);
    hv[0] = f2bf(h[0]); hv[1] = f2bf(h[1]); hv[2] = f2bf(h[2]); hv[3] = f2bf(h[3]);
    *(s16x4*)&P[o]    = pv;
    *(s16x4*)&hend[o] = hv;
}

__global__ __launch_bounds__(256) void scan_pass2(
    const short* __restrict__ P, const short* __restrict__ hend,
    short* __restrict__ Hstart)
{
    int idx = blockIdx.x * 256 + threadIdx.x;
    if (idx >= B_ * I_ * N_) return;
    int n = idx & 15;
    int i = (idx >> 4) % I_;
    int b = idx / (I_ * N_);
    float H = 0.f;
    #pragma unroll
    for (int c = 0; c < C_ - 1; ++c) {
        size_t o = (((size_t)b * C_ + c) * I_ + i) * (size_t)N_ + n;
        Hstart[o] = f2bf(H);
        H = fmaf(bf2f(P[o]), H, bf2f(hend[o]));
    }
    size_t o15 = (((size_t)b * C_ + (C_ - 1)) * I_ + i) * (size_t)N_ + n;
    Hstart[o15] = f2bf(H);
}

__global__ __launch_bounds__(256) void scan_pass3(
    const short* __restrict__ xcbf, const short* __restrict__ dtbf,
    const float* __restrict__ dbc, const short* __restrict__ xzbf,
    const float* __restrict__ A_log, const float* __restrict__ D,
    const short* __restrict__ Hstart, short* __restrict__ y16)
{
    __shared__ float Bsh[T_][16];
    __shared__ float Csh[T_][16];
    __shared__ float dtsh[T_][64];
    __shared__ float xcsh[T_][64];
    __shared__ float zsh[T_][64];
    __shared__ short ysh[T_][64];
    const int tid = threadIdx.x;
    const int lc  = tid >> 2;
    const int sub = tid & 3;
    const int ib  = blockIdx.x % (I_ / 64);
    const int c   = (blockIdx.x / (I_ / 64)) % C_;
    const int b   = blockIdx.x / ((I_ / 64) * C_);
    const int i   = ib * 64 + lc;
    const int s0  = c * T_;

    for (int idx = tid; idx < T_ * 4; idx += 256) {
        int row = idx >> 2, q = idx & 3;
        const float* src = &dbc[((size_t)b * S_ + s0 + row) * 80 + R_];
        *(float4*)&Bsh[row][q * 4] = *(const float4*)&src[q * 4];
        *(float4*)&Csh[row][q * 4] = *(const float4*)&src[16 + q * 4];
    }
    for (int idx = tid; idx < T_ * 16; idx += 256) {
        int row = idx >> 4, q = idx & 15;
        size_t g = ((size_t)b * S_ + s0 + row) * I_ + ib * 64 + q * 4;
        s16x4 dv = *(const s16x4*)&dtbf[g];
        dtsh[row][q * 4 + 0] = bf2f(dv[0]);
        dtsh[row][q * 4 + 1] = bf2f(dv[1]);
        dtsh[row][q * 4 + 2] = bf2f(dv[2]);
        dtsh[row][q * 4 + 3] = bf2f(dv[3]);
        s16x4 xv = *(const s16x4*)&xcbf[g];
        xcsh[row][q * 4 + 0] = bf2f(xv[0]);
        xcsh[row][q * 4 + 1] = bf2f(xv[1]);
        xcsh[row][q * 4 + 2] = bf2f(xv[2]);
        xcsh[row][q * 4 + 3] = bf2f(xv[3]);
        size_t gz = ((size_t)b * S_ + s0 + row) * (2 * I_) + I_ + ib * 64 + q * 4;
        s16x4 zv = *(const s16x4*)&xzbf[gz];
        zsh[row][q * 4 + 0] = bf2f(zv[0]);
        zsh[row][q * 4 + 1] = bf2f(zv[1]);
        zsh[row][q * 4 + 2] = bf2f(zv[2]);
        zsh[row][q * 4 + 3] = bf2f(zv[3]);
    }

    float4 al = *(const float4*)&A_log[i * N_ + sub * 4];
    float a[4] = {-fexpf(al.x), -fexpf(al.y), -fexpf(al.z), -fexpf(al.w)};
    const float Dv = D[i];

    size_t ho = (((size_t)b * C_ + c) * I_ + i) * N_ + sub * 4;
    s16x4 h0 = *(const s16x4*)&Hstart[ho];
    float h[4] = {bf2f(h0[0]), bf2f(h0[1]), bf2f(h0[2]), bf2f(h0[3])};
    __syncthreads();

    #pragma unroll 4
    for (int s = 0; s < T_; ++s) {
        float dtv = dtsh[s][lc];
        float xcv = xcsh[s][lc];
        float4 Bv = *(const float4*)&Bsh[s][sub * 4];
        float4 Cv = *(const float4*)&Csh[s][sub * 4];
        float dx = dtv * xcv;
        float yv;
        {
            float dA0 = fexpf(dtv * a[0]);
            float dA1 = fexpf(dtv * a[1]);
            float dA2 = fexpf(dtv * a[2]);
            float dA3 = fexpf(dtv * a[3]);
            h[0] = fmaf(dA0, h[0], dx * Bv.x);
            h[1] = fmaf(dA1, h[1], dx * Bv.y);
            h[2] = fmaf(dA2, h[2], dx * Bv.z);
            h[3] = fmaf(dA3, h[3], dx * Bv.w);
            yv = h[0] * Cv.x;
            yv = fmaf(h[1], Cv.y, yv);
            yv = fmaf(h[2], Cv.z, yv);
            yv = fmaf(h[3], Cv.w, yv);
        }
        yv += __shfl_xor(yv, 1, 4);
        yv += __shfl_xor(yv, 2, 4);
        if (sub == 0) {
            float zv = zsh[s][lc];
            ysh[s][lc] = f2bf((yv + xcv * Dv) * siluf(zv));
        }
    }
    __syncthreads();
    for (int idx = tid; idx < T_ * 16; idx += 256) {
        int row = idx >> 4, q = idx & 15;
        size_t g = ((size_t)b * S_ + s0 + row) * I_ + ib * 64 + q * 4;
        *(s16x4*)&y16[g] = *(const s16x4*)&ysh[row][q * 4];
    }
}

// ---------------------------------------------------------------------------
extern "C" void kernel_launch(void* const* d_in, const int* in_sizes, int n_in,
                              void* d_out, int out_size, void* d_ws, size_t ws_size,
                              hipStream_t stream)
{
    const float* x     = (const float*)d_in[0];
    const float* W_in  = (const float*)d_in[1];
    const float* b_in  = (const float*)d_in[2];
    const float* norm_w= (const float*)d_in[3];
    const float* ipw   = (const float*)d_in[4];
    const float* cw    = (const float*)d_in[5];
    const float* cb    = (const float*)d_in[6];
    const float* xpw   = (const float*)d_in[7];
    const float* dpw   = (const float*)d_in[8];
    const float* dpb   = (const float*)d_in[9];
    const float* A_log = (const float*)d_in[10];
    const float* Dp    = (const float*)d_in[11];
    const float* opw   = (const float*)d_in[12];
    const float* nfw   = (const float*)d_in[13];
    float* out = (float*)d_out;

    // fp32 scratch
    float* wsf  = (float*)d_ws;
    float* h    = wsf;  wsf += (size_t)MROWS * H_;
    float* parts= wsf;  wsf += (size_t)3 * MROWS * H_;
    float* dbcb = wsf;  wsf += (size_t)MROWS * 80;
    // bf16 scratch
    short* wss   = (short*)wsf;
    short* x_bf  = wss;  wss += (size_t)MROWS * CIN_;
    short* u_bf  = wss;  wss += (size_t)MROWS * H_;
    short* xz_bf = wss;  wss += (size_t)MROWS * 2 * I_;
    short* xc_bf = wss;  wss += (size_t)MROWS * I_;
    short* dt_bf = wss;  wss += (size_t)MROWS * I_;
    short* y_bf  = wss;  wss += (size_t)MROWS * I_;
    short* dbc48 = wss;  wss += (size_t)MROWS * 64;
    short* Pb    = wss;  wss += (size_t)B_ * C_ * I_ * N_;
    short* heb   = wss;  wss += (size_t)B_ * C_ * I_ * N_;
    short* Hsb   = wss;  wss += (size_t)B_ * C_ * I_ * N_;
    short* WinT  = wss;  wss += (size_t)H_ * CIN_;
    short* ipwT  = wss;  wss += (size_t)L_ * 2 * I_ * H_;
    short* xpwT  = wss;  wss += (size_t)L_ * 128 * I_;
    short* opwT  = wss;  wss += (size_t)L_ * H_ * I_;
    short* dpwT  = wss;  wss += (size_t)L_ * I_ * 64;

    // x_proj split-K partials alias `parts` (dead between out_proj uses):
    // 8*2048*80 floats (5.2MB) <= 3*2048*768 floats (18.9MB)
    float* part_x = parts;

    const dim3 blk(256);
    const dim3 tblk(32, 8);

    // one-time conversions (consolidated)
    cast_bf16<<<(MROWS * CIN_ / 4 + 255) / 256, blk, 0, stream>>>(x, x_bf, MROWS * CIN_ / 4);
    wtrans<<<dim3(H_ / 32, CIN_ / 32, 1), tblk, 0, stream>>>(
        W_in, WinT, CIN_, H_, CIN_, H_, 0, 0);
    wtrans<<<dim3(2 * I_ / 32, H_ / 32, L_), tblk, 0, stream>>>(
        ipw, ipwT, H_, 2 * I_, H_, 2 * I_, (size_t)H_ * 2 * I_, (size_t)2 * I_ * H_);
    wtrans<<<dim3(128 / 32, I_ / 32, L_), tblk, 0, stream>>>(
        xpw, xpwT, I_, 80, I_, 128, (size_t)I_ * 80, (size_t)128 * I_);
    wtrans<<<dim3(H_ / 32, I_ / 32, L_), tblk, 0, stream>>>(
        opw, opwT, I_, H_, I_, H_, (size_t)I_ * H_, (size_t)H_ * I_);
    // dpw (L,48,I) -> bf16 (I,64) K-padded transpose (zeros in cols 48..63)
    wtrans<<<dim3(I_ / 32, 64 / 32, L_), tblk, 0, stream>>>(
        dpw, dpwT, R_, I_, 64, I_, (size_t)R_ * I_, (size_t)I_ * 64);

    // h = x @ W_in + b_in (split-K=2), fused reduce+bias+rms -> u_bf (layer 0)
    gemm_mfma<<<dim3(H_ / 128, MROWS / 64, 2), blk, 0, stream>>>(
        x_bf, WinT, nullptr, parts, MROWS, H_, CIN_, CIN_, CIN_, H_, 0);
    reduce_h_rms<<<MROWS, blk, 0, stream>>>(
        parts, h, b_in, norm_w, u_bf, nullptr, 2, 0);

    const int scan1_blocks = B_ * (C_ - 1) * (I_ / 64);   // 1440
    const int scan3_blocks = B_ * C_ * (I_ / 64);         // 1536
    const int conv_blocks = ((MROWS / 4) * (I_ / 4) + 255) / 256;   // 768

    for (int l = 0; l < L_; ++l) {
        // xz = u @ in_proj_w  -> bf16 only (ep=4)
        gemm_mfma<<<dim3(2 * I_ / 128, MROWS / 64, 1), blk, 0, stream>>>(
            u_bf, ipwT + (size_t)l * 2 * I_ * H_, nullptr, xz_bf,
            MROWS, 2 * I_, H_, H_, H_, 2 * I_, 4);
        conv_silu_kernel<<<conv_blocks, blk, 0, stream>>>(
            xz_bf, cw + l * I_ * K_, cb + l * I_, xc_bf);
        gemm_mfma<<<dim3(1, MROWS / 64, 8), blk, 0, stream>>>(
            xc_bf, xpwT + (size_t)l * 128 * I_, nullptr, part_x,
            MROWS, 80, I_, I_, I_, 80, 0);
        reduce_parts<<<(MROWS * 80 + 255) / 256, blk, 0, stream>>>(
            part_x, dbcb, nullptr, dbc48, MROWS * 80, 80, 8, 0);
        // dt = softplus(dbc48 @ dpwT^T + dpb) -> bf16  (MFMA, K=64 padded)
        gemm_mfma<<<dim3(I_ / 128, MROWS / 64, 1), blk, 0, stream>>>(
            dbc48, dpwT + (size_t)l * I_ * 64, dpb + (size_t)l * I_, dt_bf,
            MROWS, I_, 64, 64, 64, I_, 5);
        // chunked selective scan (bf16 inter-chunk state)
        scan_pass1<<<scan1_blocks, blk, 0, stream>>>(
            xc_bf, dt_bf, dbcb, A_log + l * I_ * N_, Pb, heb);
        scan_pass2<<<(B_ * I_ * N_ + 255) / 256, blk, 0, stream>>>(Pb, heb, Hsb);
        scan_pass3<<<scan3_blocks, blk, 0, stream>>>(
            xc_bf, dt_bf, dbcb, xz_bf, A_log + l * I_ * N_, Dp + l * I_, Hsb, y_bf);
        // h += y @ out_proj_w (split-K=3), fused reduce + h + rms
        gemm_mfma<<<dim3(H_ / 128, MROWS / 64, 3), blk, 0, stream>>>(
            y_bf, opwT + (size_t)l * H_ * I_, nullptr, parts,
            MROWS, H_, I_, I_, I_, H_, 0);
        if (l < L_ - 1) {
            reduce_h_rms<<<MROWS, blk, 0, stream>>>(
                parts, h, nullptr, norm_w + (l + 1) * H_, u_bf, nullptr, 3, 1);
        } else {
            reduce_h_rms<<<MROWS, blk, 0, stream>>>(
                parts, h, nullptr, nfw, nullptr, out, 3, 2);
        }
    }
}